// Round 3
// baseline (209.211 us; speedup 1.0000x reference)
//
#include <hip/hip_runtime.h>
#include <math.h>

typedef __bf16 bf16;
typedef __attribute__((ext_vector_type(8))) __bf16 bf16x8;
typedef __attribute__((ext_vector_type(4))) float f32x4;
typedef __attribute__((ext_vector_type(16))) float f32x16;
typedef unsigned short u16;
typedef unsigned int u32;

constexpr int Nn = 8, Cc = 512, Ll = 2048, Hh = 8, Dd = 64;
constexpr float kScale = 0.044194173824159216f;           // 512^-0.5
constexpr float kQexp2 = kScale * 1.44269504088896341f;   // fold log2(e) into Q
constexpr size_t NCL = (size_t)Nn * Cc * Ll;
constexpr size_t WSZ = (size_t)Cc * Cc;

static __device__ __forceinline__ u16 bfbits(bf16 v) {
    union { bf16 b; u16 u; } x; x.b = v; return x.u;
}
static __device__ __forceinline__ float fexp2(float x) {
#if __has_builtin(__builtin_amdgcn_exp2f)
    return __builtin_amdgcn_exp2f(x);
#else
    return exp2f(x);
#endif
}

#define MFMA(a, b, c) __builtin_amdgcn_mfma_f32_16x16x32_bf16((a), (b), (c), 0, 0, 0)
#define MFMA32(a, b, c) __builtin_amdgcn_mfma_f32_32x32x16_bf16((a), (b), (c), 0, 0, 0)

static __device__ __forceinline__ void async16(const bf16* g, bf16* l) {
    __builtin_amdgcn_global_load_lds(
        (const __attribute__((address_space(1))) void*)g,
        (__attribute__((address_space(3))) void*)l, 16, 0, 0);
}

// pack two f32 -> one dword of 2 bf16 (RNE), lo in low half
static __device__ __forceinline__ u32 cvtpk(float lo, float hi) {
    u32 d;
    asm("v_cvt_pk_bf16_f32 %0, %1, %2" : "=v"(d) : "v"(lo), "v"(hi));
    return d;
}
// v_permlane32_swap_b32 vdst, vsrc:
//   vdst lanes[32:63] <-> vsrc lanes[0:31]
//   => dst_new = [dst_lo | src_lo], src_new = [dst_hi | src_hi]
static __device__ __forceinline__ void swap32(u32& d, u32& s) {
    asm volatile("v_permlane32_swap_b32 %0, %1" : "+v"(d), "+v"(s));
}

// ---------------------------------------------------------------------------
// prep: z<8 -> x [n][c][l] fp32 -> xT [n][l][c] bf16 (64x64 tiles via LDS);
//       z==8 -> weights fp32 -> bf16.  grid (32, 8, 9), block 256.
// ---------------------------------------------------------------------------
__global__ __launch_bounds__(256) void prep_kernel(
    const float* __restrict__ x,
    const float* __restrict__ Wq, const float* __restrict__ Wk,
    const float* __restrict__ Wv, const float* __restrict__ Wo,
    bf16* __restrict__ xT, bf16* __restrict__ Wb)
{
    const int tid = threadIdx.x;
    if (blockIdx.z == Nn) {
        int gid = (blockIdx.y * 32 + blockIdx.x) * 256 + tid;   // 0..65535
        int w = gid >> 14;
        int o = (gid & 16383) * 4;                              // float4 base
        const float* src = (w == 0) ? Wq : (w == 1) ? Wk : (w == 2) ? Wv : Wo;
        bf16* dst = Wb + (size_t)w * WSZ;
#pragma unroll
        for (int j = 0; j < 4; j++) {
            float4 v = ((const float4*)src)[o + j];
            ushort4 u;
            u.x = bfbits((bf16)v.x); u.y = bfbits((bf16)v.y);
            u.z = bfbits((bf16)v.z); u.w = bfbits((bf16)v.w);
            *(ushort4*)(dst + (size_t)(o + j) * 4) = u;
        }
        return;
    }

    __shared__ bf16 Ts[64][72];
    const int lt = blockIdx.x, ct = blockIdx.y, n = blockIdx.z;

    const int cr = tid >> 2, l0 = (tid & 3) * 16;
    const float* src = x + ((size_t)(n * Cc + ct * 64 + cr)) * Ll + lt * 64 + l0;
#pragma unroll
    for (int i = 0; i < 4; i++) {
        float4 v = *(const float4*)(src + i * 4);
        Ts[l0 + i * 4 + 0][cr] = (bf16)v.x;
        Ts[l0 + i * 4 + 1][cr] = (bf16)v.y;
        Ts[l0 + i * 4 + 2][cr] = (bf16)v.z;
        Ts[l0 + i * 4 + 3][cr] = (bf16)v.w;
    }
    __syncthreads();

    const int lr = tid >> 2, c0 = (tid & 3) * 16;
    bf16* dst = xT + ((size_t)(n * Ll + lt * 64 + lr)) * Cc + ct * 64 + c0;
    *(bf16x8*)(dst)     = *(const bf16x8*)&Ts[lr][c0];
    *(bf16x8*)(dst + 8) = *(const bf16x8*)&Ts[lr][c0 + 8];
}

// ---------------------------------------------------------------------------
// QKV GEMM (m97 structure, unchanged). Q pre-scaled by kScale*log2e.
// ---------------------------------------------------------------------------
__global__ __launch_bounds__(256) void qkv_gemm(
    const bf16* __restrict__ xT, const bf16* __restrict__ Wb,
    bf16* __restrict__ Qt, bf16* __restrict__ Kt, bf16* __restrict__ Vb)
{
    const int lt = blockIdx.x, ow = blockIdx.y, n = blockIdx.z;
    const int widx = ow >> 2, otile = ow & 3;

    __shared__ bf16 Xs[128 * 64];
    __shared__ bf16 Ws[128 * 64];

    const int tid = threadIdx.x;
    const int lane = tid & 63, wv = tid >> 6;
    const int m = lane & 15, quad = lane >> 4;
    const int rh = wv & 1, ch = wv >> 1;

    const bf16* __restrict__ W = Wb + (size_t)widx * WSZ + (size_t)otile * 128 * Cc;
    const bf16* __restrict__ X = xT + (size_t)(n * Ll + lt * 128) * Cc;

    int srow[4], scol[4];
#pragma unroll
    for (int i = 0; i < 4; i++) {
        int q = i * 256 + tid;
        srow[i] = q >> 3;
        scol[i] = ((q ^ (q >> 3)) & 7) * 8;
    }

    f32x4 acc[4][4] = {};

    for (int c0 = 0; c0 < Cc; c0 += 64) {
#pragma unroll
        for (int i = 0; i < 4; i++)
            async16(&X[(size_t)srow[i] * Cc + c0 + scol[i]], &Xs[(i * 256 + tid) * 8]);
#pragma unroll
        for (int i = 0; i < 4; i++)
            async16(&W[(size_t)srow[i] * Cc + c0 + scol[i]], &Ws[(i * 256 + tid) * 8]);
        __syncthreads();

        const bf16* TA = (widx < 2) ? Xs : Ws;
        const bf16* TB = (widx < 2) ? Ws : Xs;
#pragma unroll
        for (int kk = 0; kk < 2; kk++) {
            const int sw = (((kk * 4 + quad) ^ (m & 7)) * 8);
            bf16x8 af[4], bfr[4];
#pragma unroll
            for (int t = 0; t < 4; t++)
                af[t] = *(const bf16x8*)&TA[(rh * 64 + t * 16 + m) * 64 + sw];
#pragma unroll
            for (int u = 0; u < 4; u++)
                bfr[u] = *(const bf16x8*)&TB[(ch * 64 + u * 16 + m) * 64 + sw];
#pragma unroll
            for (int t = 0; t < 4; t++)
#pragma unroll
                for (int u = 0; u < 4; u++)
                    acc[t][u] = MFMA(af[t], bfr[u], acc[t][u]);
        }
        __syncthreads();
    }

    if (widx < 2) {
        const float fq = (widx == 0) ? kQexp2 : 1.0f;
        bf16* __restrict__ OUT = (widx == 0) ? Qt : Kt;
#pragma unroll
        for (int u = 0; u < 4; u++) {
            const int o = otile * 128 + ch * 64 + u * 16 + m;
            const int h = o >> 6, d = o & 63;
            bf16* base = OUT + (size_t)(n * Hh + h) * Ll * Dd + d;
#pragma unroll
            for (int t = 0; t < 4; t++) {
                const int l0 = lt * 128 + rh * 64 + t * 16 + quad * 4;
#pragma unroll
                for (int r = 0; r < 4; r++)
                    base[(size_t)(l0 + r) * Dd] = (bf16)(acc[t][u][r] * fq);
            }
        }
    } else {
#pragma unroll
        for (int t = 0; t < 4; t++) {
            const int ob = otile * 128 + rh * 64 + t * 16 + quad * 4;
#pragma unroll
            for (int r = 0; r < 4; r++) {
                const int oo = ob + r, h = oo >> 6, d = oo & 63;
                bf16* base = Vb + ((size_t)(n * Hh + h) * Dd + d) * Ll;
#pragma unroll
                for (int u = 0; u < 4; u++)
                    base[lt * 128 + ch * 64 + u * 16 + m] = (bf16)acc[t][u][r];
            }
        }
    }
}

// ---------------------------------------------------------------------------
// Causal attention v10: 32x32x16 MFMA + in-register softmax (T12 structure).
// St^T = K x Q puts q in-lane (col=lane&31); P -> PV A-frag redistribution is
// 4 cvt_pk + 2 permlane32_swap per 16-k step (pure VALU) -> no P LDS round
// trip, no lgkmcnt(0) stall. permlane32_swap semantics: dst_hi <-> src_lo,
// so swap32(A,C)/swap32(B,D) with frag=[A,B,C,D] gives lo-lane k0..7 and
// hi-lane k8..15 (v9 had the direction inverted -> NaN via Ltot=0 rows).
// One 128-q supertile per block (4 waves x 32 q); grid (h, 16, n) = 1024
// blocks, biggest-first (st = 15 - y) -> 4 blocks/CU, 16 waves/CU. LDS 33 KB.
// Per-wave LDS traffic 16 KB/iter (K+V only). Causal: wave diag tile =
// 2*st + (wv>>1); on diag, even waves skip the upper k-half entirely, mask
// kc > lane&31 on the aligned half.
// ---------------------------------------------------------------------------
__global__ __launch_bounds__(256, 4) void attn_mfma(
    const bf16* __restrict__ Qt, const bf16* __restrict__ Kt,
    const bf16* __restrict__ Vb, bf16* __restrict__ AO)
{
    const int h  = blockIdx.x;
    const int st = 15 - (int)blockIdx.y;   // big blocks dispatched first
    const int n  = blockIdx.z;

    __shared__ bf16 KV[2][2][64 * 64];   // [buf][K=0 / V^T=1] 32 KB
    __shared__ float Lsc[4][32];         // per-wave row-sum scratch

    const int tid = threadIdx.x;
    const int lane = tid & 63, wv = tid >> 6;
    const int l31 = lane & 31, hb = lane >> 5;
    const int sw7 = l31 & 7;

    const size_t bnh = (size_t)(n * Hh + h) * Ll * Dd;
    const bf16* __restrict__ Qh = Qt + bnh;
    const bf16* __restrict__ Kh = Kt + bnh;
    const bf16* __restrict__ Vh = Vb + bnh;

    const int srow = tid >> 3;                           // 0..31 (and +32)
    const int scs  = (((tid & 7) ^ (srow & 7)) * 8);     // swizzled global chunk

    const int nk    = 2 * st + 2;
    const int dtile = 2 * st + (wv >> 1);   // this wave's diagonal k-tile
    const int mhalf = wv & 1;               // which k-half is triangular on diag
    const int qrow0 = st * 128 + wv * 32;

    // Q as B-fragments: lane holds Q[q=qrow0+l31][d = s*16 + hb*8 + 0..7]
    bf16x8 qf[4];
#pragma unroll
    for (int s = 0; s < 4; s++)
        qf[s] = *(const bf16x8*)&Qh[(size_t)(qrow0 + l31) * Dd + s * 16 + hb * 8];

    f32x16 O0 = {}, O1 = {};
    float Lacc = 0.f;

    // stage tile 0 -> buf 0
    async16(&Kh[(size_t)srow * Dd + scs],        &KV[0][0][(size_t)tid * 8]);
    async16(&Kh[(size_t)(srow + 32) * Dd + scs], &KV[0][0][(size_t)tid * 8 + 2048]);
    async16(&Vh[(size_t)srow * Ll + scs],        &KV[0][1][(size_t)tid * 8]);
    async16(&Vh[(size_t)(srow + 32) * Ll + scs], &KV[0][1][(size_t)tid * 8 + 2048]);
    __syncthreads();   // drains asyncs

    for (int kt = 0; kt < nk; kt++) {
        const int cur = kt & 1;

        if (kt + 1 < nk) {   // prefetch next tile into the other buffer
            const int kn = (kt + 1) * 64;
            async16(&Kh[(size_t)(kn + srow) * Dd + scs],      &KV[cur ^ 1][0][(size_t)tid * 8]);
            async16(&Kh[(size_t)(kn + srow + 32) * Dd + scs], &KV[cur ^ 1][0][(size_t)tid * 8 + 2048]);
            async16(&Vh[(size_t)srow * Ll + kn + scs],        &KV[cur ^ 1][1][(size_t)tid * 8]);
            async16(&Vh[(size_t)(srow + 32) * Ll + kn + scs], &KV[cur ^ 1][1][(size_t)tid * 8 + 2048]);
        }

        if (kt <= dtile) {   // wave-uniform
            const bf16* Ks = &KV[cur][0][0];
            const bf16* Vs = &KV[cur][1][0];
            const bool dg = (kt == dtile);

#pragma unroll
            for (int i = 0; i < 2; i++) {
                // on diag, even waves: upper k-half fully masked -> skip
                if (i == 1 && dg && mhalf == 0) continue;

                // St^T[k = 32i + koff][q = l31], koff = (r&3)+8*(r>>2)+4*hb
                f32x16 St = {};
#pragma unroll
                for (int s = 0; s < 4; s++) {
                    bf16x8 kfs = *(const bf16x8*)
                        &Ks[(32 * i + l31) * 64 + (((2 * s + hb) ^ sw7) * 8)];
                    St = MFMA32(kfs, qf[s], St);
                }

                const bool msk = dg && (i == mhalf);

#pragma unroll
                for (int s = 0; s < 2; s++) {
                    // V^T reads (independent of softmax -> issue early)
                    const int c0 = 4 * i + 2 * s + hb;
                    bf16x8 v0 = *(const bf16x8*)&Vs[l31 * 64 + ((c0 ^ sw7) * 8)];
                    bf16x8 v1 = *(const bf16x8*)&Vs[(32 + l31) * 64 + ((c0 ^ sw7) * 8)];

                    float p[8];
#pragma unroll
                    for (int j = 0; j < 8; j++) {
                        const int r = s * 8 + j;
                        float pv = fexp2(St[r]);
                        if (msk) {
                            const int kc = (r & 3) + 8 * (r >> 2) + 4 * hb;
                            if (kc > l31) pv = 0.f;
                        }
                        p[j] = pv;
                    }
                    Lacc += ((p[0] + p[1]) + (p[2] + p[3]))
                          + ((p[4] + p[5]) + (p[6] + p[7]));

                    // lane values after cvtpk (lo-lane / hi-lane):
                    //   A: k(0,1)/k(4,5)  B: k(2,3)/k(6,7)
                    //   C: k(8,9)/k(12,13) D: k(10,11)/k(14,15)
                    u32 A = cvtpk(p[0], p[1]);
                    u32 B = cvtpk(p[2], p[3]);
                    u32 C = cvtpk(p[4], p[5]);
                    u32 D = cvtpk(p[6], p[7]);
                    // dst_hi <-> src_lo:
                    //   A=[A_lo|C_lo], C=[A_hi|C_hi]; B=[B_lo|D_lo], D=[B_hi|D_hi]
                    // lo-lane frag = k(0..7), hi-lane frag = k(8..15)
                    swap32(A, C);
                    swap32(B, D);
                    union { u32 w[4]; bf16x8 v; } pu;
                    pu.w[0] = A; pu.w[1] = B; pu.w[2] = C; pu.w[3] = D;

                    O0 = MFMA32(pu.v, v0, O0);
                    O1 = MFMA32(pu.v, v1, O1);
                }
            }
        }

        __syncthreads();   // single barrier: drains prefetch asyncs + flips buffers
    }

    // ---- epilogue: Ltot = own + partner half (semantics-agnostic: after
    // swap32(u,w), one register holds own and the other partner in every
    // lane, so u+w = full row sum), normalize, store ----
    {
        float u = Lacc, w = Lacc;
        {
            u32 uu, ww;
            __builtin_memcpy(&uu, &u, 4);
            __builtin_memcpy(&ww, &w, 4);
            swap32(uu, ww);
            __builtin_memcpy(&u, &uu, 4);
            __builtin_memcpy(&w, &ww, 4);
        }
        const float Ltot = u + w;
        Lsc[wv][l31] = Ltot;   // same-wave LDS, both halves write same value

        const size_t aobase = (size_t)n * Ll * Cc + (size_t)h * 64;
#pragma unroll
        for (int r = 0; r < 16; r++) {
            const int qr = (r & 3) + 8 * (r >> 2) + 4 * hb;
            const float inv = 1.0f / Lsc[wv][qr];
            const size_t row = aobase + (size_t)(qrow0 + qr) * Cc;
            AO[row + l31]      = (bf16)(O0[r] * inv);
            AO[row + 32 + l31] = (bf16)(O1[r] * inv);
        }
    }
}

// ---------------------------------------------------------------------------
// Output GEMM (m97 structure, unchanged), fp32 out + bias.
// ---------------------------------------------------------------------------
__global__ __launch_bounds__(256) void out_gemm(
    const bf16* __restrict__ AO, const bf16* __restrict__ Wb,
    const float* __restrict__ bo, float* __restrict__ out)
{
    const int lt = blockIdx.x, ot = blockIdx.y, n = blockIdx.z;

    __shared__ bf16 Ws[128 * 64];
    __shared__ bf16 Bs[128 * 64];

    const int tid = threadIdx.x;
    const int lane = tid & 63, wv = tid >> 6;
    const int m = lane & 15, quad = lane >> 4;
    const int rh = wv & 1, ch = wv >> 1;

    const bf16* __restrict__ W = Wb + 3 * WSZ + (size_t)ot * 128 * Cc;
    const bf16* __restrict__ B = AO + (size_t)(n * Ll + lt * 128) * Cc;

    int srow[4], scol[4];
#pragma unroll
    for (int i = 0; i < 4; i++) {
        int q = i * 256 + tid;
        srow[i] = q >> 3;
        scol[i] = ((q ^ (q >> 3)) & 7) * 8;
    }

    f32x4 acc[4][4] = {};

    for (int c0 = 0; c0 < Cc; c0 += 64) {
#pragma unroll
        for (int i = 0; i < 4; i++)
            async16(&W[(size_t)srow[i] * Cc + c0 + scol[i]], &Ws[(i * 256 + tid) * 8]);
#pragma unroll
        for (int i = 0; i < 4; i++)
            async16(&B[(size_t)srow[i] * Cc + c0 + scol[i]], &Bs[(i * 256 + tid) * 8]);
        __syncthreads();

#pragma unroll
        for (int kk = 0; kk < 2; kk++) {
            const int sw = (((kk * 4 + quad) ^ (m & 7)) * 8);
            bf16x8 af[4], bfr[4];
#pragma unroll
            for (int t = 0; t < 4; t++)
                af[t] = *(const bf16x8*)&Ws[(rh * 64 + t * 16 + m) * 64 + sw];
#pragma unroll
            for (int u = 0; u < 4; u++)
                bfr[u] = *(const bf16x8*)&Bs[(ch * 64 + u * 16 + m) * 64 + sw];
#pragma unroll
            for (int t = 0; t < 4; t++)
#pragma unroll
                for (int u = 0; u < 4; u++)
                    acc[t][u] = MFMA(af[t], bfr[u], acc[t][u]);
        }
        __syncthreads();
    }

#pragma unroll
    for (int t = 0; t < 4; t++) {
        const int ob = ot * 128 + rh * 64 + t * 16 + quad * 4;
#pragma unroll
        for (int r = 0; r < 4; r++) {
            const int o = ob + r;
            const float b = bo[o];
            float* base = out + ((size_t)n * Cc + o) * Ll + lt * 128 + ch * 64;
#pragma unroll
            for (int u = 0; u < 4; u++)
                base[u * 16 + m] = acc[t][u][r] + b;
        }
    }
}

// ---------------------------------------------------------------------------
extern "C" void kernel_launch(void* const* d_in, const int* in_sizes, int n_in,
                              void* d_out, int out_size, void* d_ws, size_t ws_size,
                              hipStream_t stream)
{
    const float* x  = (const float*)d_in[0];
    const float* Wq = (const float*)d_in[1];
    const float* Wk = (const float*)d_in[2];
    const float* Wv = (const float*)d_in[3];
    const float* Wo = (const float*)d_in[4];
    const float* bo = (const float*)d_in[5];
    float* out = (float*)d_out;

    bf16* ws = (bf16*)d_ws;
    bf16* xT = ws;                        // [n][l][c]
    bf16* Wb = xT + NCL;                  // 4 x 512x512
    bf16* Qt = Wb + 4 * WSZ;              // [n][h][l][d]  (pre-scaled)
    bf16* Kt = Qt + NCL;                  // [n][h][l][d]
    bf16* Vb = Kt + NCL;                  // [n][h][d][l]
    bf16* AO = Vb + NCL;                  // [n][l][c]

    prep_kernel<<<dim3(32, 8, Nn + 1), 256, 0, stream>>>(x, Wq, Wk, Wv, Wo, xT, Wb);
    qkv_gemm<<<dim3(16, 12, Nn), 256, 0, stream>>>(xT, Wb, Qt, Kt, Vb);
    attn_mfma<<<dim3(Hh, 16, Nn), 256, 0, stream>>>(Qt, Kt, Vb, AO);
    out_gemm<<<dim3(16, 4, Nn), 256, 0, stream>>>(AO, Wb, bo, out);
}

// Round 9
// 191.202 us; speedup vs baseline: 1.0942x; 1.0942x over previous
//
#include <hip/hip_runtime.h>
#include <math.h>

typedef __bf16 bf16;
typedef __attribute__((ext_vector_type(8))) __bf16 bf16x8;
typedef __attribute__((ext_vector_type(4))) float f32x4;
typedef __attribute__((ext_vector_type(16))) float f32x16;
typedef unsigned short u16;
typedef unsigned int u32;

constexpr int Nn = 8, Cc = 512, Ll = 2048, Hh = 8, Dd = 64;
constexpr float kScale = 0.044194173824159216f;           // 512^-0.5
constexpr float kQexp2 = kScale * 1.44269504088896341f;   // fold log2(e) into Q
constexpr size_t NCL = (size_t)Nn * Cc * Ll;
constexpr size_t WSZ = (size_t)Cc * Cc;

static __device__ __forceinline__ u16 bfbits(bf16 v) {
    union { bf16 b; u16 u; } x; x.b = v; return x.u;
}
static __device__ __forceinline__ float fexp2(float x) {
#if __has_builtin(__builtin_amdgcn_exp2f)
    return __builtin_amdgcn_exp2f(x);
#else
    return exp2f(x);
#endif
}

#define MFMA(a, b, c) __builtin_amdgcn_mfma_f32_16x16x32_bf16((a), (b), (c), 0, 0, 0)
#define MFMA32(a, b, c) __builtin_amdgcn_mfma_f32_32x32x16_bf16((a), (b), (c), 0, 0, 0)

static __device__ __forceinline__ void async16(const bf16* g, bf16* l) {
    __builtin_amdgcn_global_load_lds(
        (const __attribute__((address_space(1))) void*)g,
        (__attribute__((address_space(3))) void*)l, 16, 0, 0);
}

// pack two f32 -> one dword of 2 bf16 (RNE), lo in low half
static __device__ __forceinline__ u32 cvtpk(float lo, float hi) {
    u32 d;
    asm("v_cvt_pk_bf16_f32 %0, %1, %2" : "=v"(d) : "v"(lo), "v"(hi));
    return d;
}
// v_permlane32_swap_b32 vdst, vsrc: vdst lanes[32:63] <-> vsrc lanes[0:31]
//   => dst_new = [dst_lo | src_lo], src_new = [dst_hi | src_hi]
// NOTE: only safe with DISTINCT-valued operands (regalloc can coalesce
// equal-valued registers into one -> swap_b32 v,v destroys a half; this was
// the epilogue-L NaN root cause in v11/v12). All uses below have distinct
// cvtpk results as operands (the form v10 compiled + passed with).
static __device__ __forceinline__ void swap32(u32& d, u32& s) {
    asm volatile("v_permlane32_swap_b32 %0, %1" : "+v"(d), "+v"(s));
}

// ---------------------------------------------------------------------------
// prep: z<8 -> x [n][c][l] fp32 -> xT [n][l][c] bf16 (64x64 tiles via LDS);
//       z==8 -> weights fp32 -> bf16.  grid (32, 8, 9), block 256.
// ---------------------------------------------------------------------------
__global__ __launch_bounds__(256) void prep_kernel(
    const float* __restrict__ x,
    const float* __restrict__ Wq, const float* __restrict__ Wk,
    const float* __restrict__ Wv, const float* __restrict__ Wo,
    bf16* __restrict__ xT, bf16* __restrict__ Wb)
{
    const int tid = threadIdx.x;
    if (blockIdx.z == Nn) {
        int gid = (blockIdx.y * 32 + blockIdx.x) * 256 + tid;   // 0..65535
        int w = gid >> 14;
        int o = (gid & 16383) * 4;                              // float4 base
        const float* src = (w == 0) ? Wq : (w == 1) ? Wk : (w == 2) ? Wv : Wo;
        bf16* dst = Wb + (size_t)w * WSZ;
#pragma unroll
        for (int j = 0; j < 4; j++) {
            float4 v = ((const float4*)src)[o + j];
            ushort4 u;
            u.x = bfbits((bf16)v.x); u.y = bfbits((bf16)v.y);
            u.z = bfbits((bf16)v.z); u.w = bfbits((bf16)v.w);
            *(ushort4*)(dst + (size_t)(o + j) * 4) = u;
        }
        return;
    }

    __shared__ bf16 Ts[64][72];
    const int lt = blockIdx.x, ct = blockIdx.y, n = blockIdx.z;

    const int cr = tid >> 2, l0 = (tid & 3) * 16;
    const float* src = x + ((size_t)(n * Cc + ct * 64 + cr)) * Ll + lt * 64 + l0;
#pragma unroll
    for (int i = 0; i < 4; i++) {
        float4 v = *(const float4*)(src + i * 4);
        Ts[l0 + i * 4 + 0][cr] = (bf16)v.x;
        Ts[l0 + i * 4 + 1][cr] = (bf16)v.y;
        Ts[l0 + i * 4 + 2][cr] = (bf16)v.z;
        Ts[l0 + i * 4 + 3][cr] = (bf16)v.w;
    }
    __syncthreads();

    const int lr = tid >> 2, c0 = (tid & 3) * 16;
    bf16* dst = xT + ((size_t)(n * Ll + lt * 64 + lr)) * Cc + ct * 64 + c0;
    *(bf16x8*)(dst)     = *(const bf16x8*)&Ts[lr][c0];
    *(bf16x8*)(dst + 8) = *(const bf16x8*)&Ts[lr][c0 + 8];
}

// ---------------------------------------------------------------------------
// QKV GEMM (m97 structure, unchanged). Q pre-scaled by kScale*log2e.
// ---------------------------------------------------------------------------
__global__ __launch_bounds__(256) void qkv_gemm(
    const bf16* __restrict__ xT, const bf16* __restrict__ Wb,
    bf16* __restrict__ Qt, bf16* __restrict__ Kt, bf16* __restrict__ Vb)
{
    const int lt = blockIdx.x, ow = blockIdx.y, n = blockIdx.z;
    const int widx = ow >> 2, otile = ow & 3;

    __shared__ bf16 Xs[128 * 64];
    __shared__ bf16 Ws[128 * 64];

    const int tid = threadIdx.x;
    const int lane = tid & 63, wv = tid >> 6;
    const int m = lane & 15, quad = lane >> 4;
    const int rh = wv & 1, ch = wv >> 1;

    const bf16* __restrict__ W = Wb + (size_t)widx * WSZ + (size_t)otile * 128 * Cc;
    const bf16* __restrict__ X = xT + (size_t)(n * Ll + lt * 128) * Cc;

    int srow[4], scol[4];
#pragma unroll
    for (int i = 0; i < 4; i++) {
        int q = i * 256 + tid;
        srow[i] = q >> 3;
        scol[i] = ((q ^ (q >> 3)) & 7) * 8;
    }

    f32x4 acc[4][4] = {};

    for (int c0 = 0; c0 < Cc; c0 += 64) {
#pragma unroll
        for (int i = 0; i < 4; i++)
            async16(&X[(size_t)srow[i] * Cc + c0 + scol[i]], &Xs[(i * 256 + tid) * 8]);
#pragma unroll
        for (int i = 0; i < 4; i++)
            async16(&W[(size_t)srow[i] * Cc + c0 + scol[i]], &Ws[(i * 256 + tid) * 8]);
        __syncthreads();

        const bf16* TA = (widx < 2) ? Xs : Ws;
        const bf16* TB = (widx < 2) ? Ws : Xs;
#pragma unroll
        for (int kk = 0; kk < 2; kk++) {
            const int sw = (((kk * 4 + quad) ^ (m & 7)) * 8);
            bf16x8 af[4], bfr[4];
#pragma unroll
            for (int t = 0; t < 4; t++)
                af[t] = *(const bf16x8*)&TA[(rh * 64 + t * 16 + m) * 64 + sw];
#pragma unroll
            for (int u = 0; u < 4; u++)
                bfr[u] = *(const bf16x8*)&TB[(ch * 64 + u * 16 + m) * 64 + sw];
#pragma unroll
            for (int t = 0; t < 4; t++)
#pragma unroll
                for (int u = 0; u < 4; u++)
                    acc[t][u] = MFMA(af[t], bfr[u], acc[t][u]);
        }
        __syncthreads();
    }

    if (widx < 2) {
        const float fq = (widx == 0) ? kQexp2 : 1.0f;
        bf16* __restrict__ OUT = (widx == 0) ? Qt : Kt;
#pragma unroll
        for (int u = 0; u < 4; u++) {
            const int o = otile * 128 + ch * 64 + u * 16 + m;
            const int h = o >> 6, d = o & 63;
            bf16* base = OUT + (size_t)(n * Hh + h) * Ll * Dd + d;
#pragma unroll
            for (int t = 0; t < 4; t++) {
                const int l0 = lt * 128 + rh * 64 + t * 16 + quad * 4;
#pragma unroll
                for (int r = 0; r < 4; r++)
                    base[(size_t)(l0 + r) * Dd] = (bf16)(acc[t][u][r] * fq);
            }
        }
    } else {
#pragma unroll
        for (int t = 0; t < 4; t++) {
            const int ob = otile * 128 + rh * 64 + t * 16 + quad * 4;
#pragma unroll
            for (int r = 0; r < 4; r++) {
                const int oo = ob + r, h = oo >> 6, d = oo & 63;
                bf16* base = Vb + ((size_t)(n * Hh + h) * Dd + d) * Ll;
#pragma unroll
                for (int u = 0; u < 4; u++)
                    base[lt * 128 + ch * 64 + u * 16 + m] = (bf16)acc[t][u][r];
            }
        }
    }
}

// ---------------------------------------------------------------------------
// Causal attention v13b = v10's verified compute (32x32x16 MFMA, in-register
// softmax via cvt_pk + permlane32_swap) + {jp,15-jp} supertile pairing for
// uniform block durations + epilogue L-sum via LDS half-partials (no
// permlane on equal-valued registers -> no regalloc-coalescing hazard).
// Grid (h, 8, n) = 512 blocks x 256 thr -> 2 blocks/CU all-resident,
// uniform 34 k-iters, zero tail / zero imbalance. LDS 33 KB/block.
// ---------------------------------------------------------------------------
__global__ __launch_bounds__(256, 4) void attn_mfma(
    const bf16* __restrict__ Qt, const bf16* __restrict__ Kt,
    const bf16* __restrict__ Vb, bf16* __restrict__ AO)
{
    const int h  = blockIdx.x;
    const int jp = blockIdx.y;   // 0..7 -> pair {jp, 15-jp}
    const int n  = blockIdx.z;

    __shared__ bf16 KV[2][2][64 * 64];   // [buf][K=0 / V^T=1] 32 KB
    __shared__ float Lsc[4][64];         // per-wave row-sum scratch (halves)

    const int tid = threadIdx.x;
    const int lane = tid & 63, wv = tid >> 6;
    const int l31 = lane & 31, hb = lane >> 5;
    const int sw7 = l31 & 7;

    const size_t bnh = (size_t)(n * Hh + h) * Ll * Dd;
    const bf16* __restrict__ Qh = Qt + bnh;
    const bf16* __restrict__ Kh = Kt + bnh;
    const bf16* __restrict__ Vh = Vb + bnh;

    const int srow = tid >> 3;                        // 0..31
    const int scs  = (((tid & 7) ^ (srow & 7)) * 8);  // swizzled global chunk
    const int mhalf = wv & 1;   // which k-half is triangular on this wave's diag

#pragma unroll 1
    for (int ph = 0; ph < 2; ph++) {
        const int st = ph ? (15 - jp) : jp;     // supertile 0..15 (128 q-rows)
        const int nk = 2 * st + 2;
        const int dtile = 2 * st + (wv >> 1);   // this wave's diagonal k-tile
        const int qrow0 = st * 128 + wv * 32;

        // Q as B-fragments: lane holds Q[q=qrow0+l31][d = s*16 + hb*8 + 0..7]
        bf16x8 qf[4];
#pragma unroll
        for (int s = 0; s < 4; s++)
            qf[s] = *(const bf16x8*)&Qh[(size_t)(qrow0 + l31) * Dd + s * 16 + hb * 8];

        f32x16 O0 = {}, O1 = {};
        float Lacc = 0.f;

        // stage tile 0 -> buf 0
        async16(&Kh[(size_t)srow * Dd + scs],        &KV[0][0][(size_t)tid * 8]);
        async16(&Kh[(size_t)(srow + 32) * Dd + scs], &KV[0][0][(size_t)tid * 8 + 2048]);
        async16(&Vh[(size_t)srow * Ll + scs],        &KV[0][1][(size_t)tid * 8]);
        async16(&Vh[(size_t)(srow + 32) * Ll + scs], &KV[0][1][(size_t)tid * 8 + 2048]);
        __syncthreads();   // drains asyncs

        for (int kt = 0; kt < nk; kt++) {
            const int cur = kt & 1;

            if (kt + 1 < nk) {   // prefetch next tile into the other buffer
                const int kn = (kt + 1) * 64;
                async16(&Kh[(size_t)(kn + srow) * Dd + scs],      &KV[cur ^ 1][0][(size_t)tid * 8]);
                async16(&Kh[(size_t)(kn + srow + 32) * Dd + scs], &KV[cur ^ 1][0][(size_t)tid * 8 + 2048]);
                async16(&Vh[(size_t)srow * Ll + kn + scs],        &KV[cur ^ 1][1][(size_t)tid * 8]);
                async16(&Vh[(size_t)(srow + 32) * Ll + kn + scs], &KV[cur ^ 1][1][(size_t)tid * 8 + 2048]);
            }

            if (kt <= dtile) {   // wave-uniform
                const bf16* Ks = &KV[cur][0][0];
                const bf16* Vs = &KV[cur][1][0];
                const bool dg = (kt == dtile);

#pragma unroll
                for (int i = 0; i < 2; i++) {
                    // on diag, lower-half waves: upper k-half fully masked -> skip
                    if (i == 1 && dg && mhalf == 0) continue;

                    // St^T[k = 32i + koff][q = l31], koff = (r&3)+8*(r>>2)+4*hb
                    f32x16 St = {};
#pragma unroll
                    for (int s = 0; s < 4; s++) {
                        bf16x8 kfs = *(const bf16x8*)
                            &Ks[(32 * i + l31) * 64 + (((2 * s + hb) ^ sw7) * 8)];
                        St = MFMA32(kfs, qf[s], St);
                    }

                    const bool msk = dg && (i == mhalf);

#pragma unroll
                    for (int s = 0; s < 2; s++) {
                        // V^T reads (independent of softmax -> issue early)
                        const int c0 = 4 * i + 2 * s + hb;
                        bf16x8 v0 = *(const bf16x8*)&Vs[l31 * 64 + ((c0 ^ sw7) * 8)];
                        bf16x8 v1 = *(const bf16x8*)&Vs[(32 + l31) * 64 + ((c0 ^ sw7) * 8)];

                        float p[8];
#pragma unroll
                        for (int j = 0; j < 8; j++) {
                            const int r = s * 8 + j;
                            float pv = fexp2(St[r]);
                            if (msk) {
                                const int kc = (r & 3) + 8 * (r >> 2) + 4 * hb;
                                if (kc > l31) pv = 0.f;
                            }
                            p[j] = pv;
                        }
                        Lacc += ((p[0] + p[1]) + (p[2] + p[3]))
                              + ((p[4] + p[5]) + (p[6] + p[7]));

                        // lane values after cvtpk (lo-lane / hi-lane):
                        //   A: k(0,1)/k(4,5)  B: k(2,3)/k(6,7)
                        //   C: k(8,9)/k(12,13) D: k(10,11)/k(14,15)
                        u32 A = cvtpk(p[0], p[1]);
                        u32 B = cvtpk(p[2], p[3]);
                        u32 C = cvtpk(p[4], p[5]);
                        u32 D = cvtpk(p[6], p[7]);
                        // dst_hi <-> src_lo:
                        //   A=[A_lo|C_lo], C=[A_hi|C_hi]; B=[B_lo|D_lo], D=[B_hi|D_hi]
                        // lo-lane frag = k(0..7), hi-lane frag = k(8..15)
                        swap32(A, C);
                        swap32(B, D);
                        union { u32 w[4]; bf16x8 v; } pu;
                        pu.w[0] = A; pu.w[1] = B; pu.w[2] = C; pu.w[3] = D;

                        O0 = MFMA32(pu.v, v0, O0);
                        O1 = MFMA32(pu.v, v1, O1);
                    }
                }
            }

            __syncthreads();   // single barrier: drains prefetch asyncs + flips buffers
        }

        // ---- epilogue: L via LDS half-partials (same-wave DS is in-order;
        // no permlane needed). Lanes l31 and l31+32 hold the two halves of
        // row q = qrow0 + l31. Then normalize in O-row layout and store. ----
        {
            Lsc[wv][hb * 32 + l31] = Lacc;            // write both half-partials
            const float a  = Lsc[wv][l31];            // lo half of row l31
            const float b  = Lsc[wv][32 + l31];       // hi half of row l31
            const float Lt = a + b;
            Lsc[wv][l31] = Lt;                        // both hb write same value

            const size_t aobase = (size_t)n * Ll * Cc + (size_t)h * 64;
#pragma unroll
            for (int r = 0; r < 16; r++) {
                const int qr = (r & 3) + 8 * (r >> 2) + 4 * hb;
                const float inv = 1.0f / Lsc[wv][qr];
                const size_t row = aobase + (size_t)(qrow0 + qr) * Cc;
                AO[row + l31]      = (bf16)(O0[r] * inv);
                AO[row + 32 + l31] = (bf16)(O1[r] * inv);
            }
        }
    }
}

// ---------------------------------------------------------------------------
// Output GEMM (m97 structure, unchanged), fp32 out + bias.
// ---------------------------------------------------------------------------
__global__ __launch_bounds__(256) void out_gemm(
    const bf16* __restrict__ AO, const bf16* __restrict__ Wb,
    const float* __restrict__ bo, float* __restrict__ out)
{
    const int lt = blockIdx.x, ot = blockIdx.y, n = blockIdx.z;

    __shared__ bf16 Ws[128 * 64];
    __shared__ bf16 Bs[128 * 64];

    const int tid = threadIdx.x;
    const int lane = tid & 63, wv = tid >> 6;
    const int m = lane & 15, quad = lane >> 4;
    const int rh = wv & 1, ch = wv >> 1;

    const bf16* __restrict__ W = Wb + 3 * WSZ + (size_t)ot * 128 * Cc;
    const bf16* __restrict__ B = AO + (size_t)(n * Ll + lt * 128) * Cc;

    int srow[4], scol[4];
#pragma unroll
    for (int i = 0; i < 4; i++) {
        int q = i * 256 + tid;
        srow[i] = q >> 3;
        scol[i] = ((q ^ (q >> 3)) & 7) * 8;
    }

    f32x4 acc[4][4] = {};

    for (int c0 = 0; c0 < Cc; c0 += 64) {
#pragma unroll
        for (int i = 0; i < 4; i++)
            async16(&W[(size_t)srow[i] * Cc + c0 + scol[i]], &Ws[(i * 256 + tid) * 8]);
#pragma unroll
        for (int i = 0; i < 4; i++)
            async16(&B[(size_t)srow[i] * Cc + c0 + scol[i]], &Bs[(i * 256 + tid) * 8]);
        __syncthreads();

#pragma unroll
        for (int kk = 0; kk < 2; kk++) {
            const int sw = (((kk * 4 + quad) ^ (m & 7)) * 8);
            bf16x8 af[4], bfr[4];
#pragma unroll
            for (int t = 0; t < 4; t++)
                af[t] = *(const bf16x8*)&Ws[(rh * 64 + t * 16 + m) * 64 + sw];
#pragma unroll
            for (int u = 0; u < 4; u++)
                bfr[u] = *(const bf16x8*)&Bs[(ch * 64 + u * 16 + m) * 64 + sw];
#pragma unroll
            for (int t = 0; t < 4; t++)
#pragma unroll
                for (int u = 0; u < 4; u++)
                    acc[t][u] = MFMA(af[t], bfr[u], acc[t][u]);
        }
        __syncthreads();
    }

#pragma unroll
    for (int t = 0; t < 4; t++) {
        const int ob = ot * 128 + rh * 64 + t * 16 + quad * 4;
#pragma unroll
        for (int r = 0; r < 4; r++) {
            const int o = ob + r;
            const float b = bo[o];
            float* base = out + ((size_t)n * Cc + o) * Ll + lt * 128 + ch * 64;
#pragma unroll
            for (int u = 0; u < 4; u++)
                base[u * 16 + m] = acc[t][u][r] + b;
        }
    }
}

// ---------------------------------------------------------------------------
extern "C" void kernel_launch(void* const* d_in, const int* in_sizes, int n_in,
                              void* d_out, int out_size, void* d_ws, size_t ws_size,
                              hipStream_t stream)
{
    const float* x  = (const float*)d_in[0];
    const float* Wq = (const float*)d_in[1];
    const float* Wk = (const float*)d_in[2];
    const float* Wv = (const float*)d_in[3];
    const float* Wo = (const float*)d_in[4];
    const float* bo = (const float*)d_in[5];
    float* out = (float*)d_out;

    bf16* ws = (bf16*)d_ws;
    bf16* xT = ws;                        // [n][l][c]
    bf16* Wb = xT + NCL;                  // 4 x 512x512
    bf16* Qt = Wb + 4 * WSZ;              // [n][h][l][d]  (pre-scaled)
    bf16* Kt = Qt + NCL;                  // [n][h][l][d]
    bf16* Vb = Kt + NCL;                  // [n][h][d][l]
    bf16* AO = Vb + NCL;                  // [n][l][c]

    prep_kernel<<<dim3(32, 8, Nn + 1), 256, 0, stream>>>(x, Wq, Wk, Wv, Wo, xT, Wb);
    qkv_gemm<<<dim3(16, 12, Nn), 256, 0, stream>>>(xT, Wb, Qt, Kt, Vb);
    attn_mfma<<<dim3(Hh, 8, Nn), 256, 0, stream>>>(Qt, Kt, Vb, AO);
    out_gemm<<<dim3(16, 4, Nn), 256, 0, stream>>>(AO, Wb, bo, out);
}